// Round 9
// baseline (639.921 us; speedup 1.0000x reference)
//
#include <hip/hip_runtime.h>
#include <hip/hip_bf16.h>

// ProtoICLHead: prototype-classifier head.
//   s = l2norm(support)  [K,128]
//   protos[c] = mean_{label==c} s          (C=256)
//   q = l2norm(query)    [M,128]
//   logits = 2 * (2*q_n@protos^T - ||q_n||^2 - ||p||^2), absent class -> -1e6
// Shapes: K=131072, M=262144, D=128, C=256. GEMM done as fp32-via-fp16-split
// (hi/lo) on MFMA: q.p = qh.ph + qh.pl + ql.ph  (lo.lo dropped, ~2^-22 rel).
// Numerics (data-distribution analysis): |q_i|~0.09, |p_i|~0.004 -> lo terms
// are fp16-denormal; even if MFMA flushes them, hi-only rounding is a random
// walk -> logit error ~1.2e-5 absolute on logits of magnitude ~2. Safe.
// Streaming arrays (q, out, sf) use nontemporal policy to keep the 128 KB
// hot B-fragment set L2-resident.

#define NCLS 256
#define DIM  128

typedef _Float16 f16x8 __attribute__((ext_vector_type(8)));
typedef _Float16 f16x4 __attribute__((ext_vector_type(4)));
typedef float    f32x4 __attribute__((ext_vector_type(4)));

// ---------------------------------------------------------------------------
// Kernel B1: per-block partial prototype sums (deterministic, no global atomics)
// LDS accumulate [256][128] fp32 (128KB) + counts, then copy to ws slot.
// Scalar per-lane loads kept deliberately: lane i -> acc[...+i] gives
// conflict-free ds_atomic (bank=lane mod 32, 2 lanes/bank = free); float2
// vectorization would make it 4-way.
// ---------------------------------------------------------------------------
__global__ __launch_bounds__(1024) void proto_partial_kernel(
    const float* __restrict__ sf, const int* __restrict__ lab,
    float* __restrict__ part, int K, int nblocks)
{
    __shared__ float acc[NCLS * DIM];   // 128 KB
    __shared__ float cnt[NCLS];

    for (int i = threadIdx.x; i < NCLS * DIM; i += 1024) acc[i] = 0.0f;
    if (threadIdx.x < NCLS) cnt[threadIdx.x] = 0.0f;
    __syncthreads();

    const int lane = threadIdx.x & 63;
    const int wid  = (blockIdx.x * 1024 + threadIdx.x) >> 6;   // global wave id
    const int nw   = (nblocks * 1024) >> 6;

    for (int row = wid; row < K; row += nw) {
        float x0 = __builtin_nontemporal_load(&sf[(size_t)row * DIM + lane]);
        float x1 = __builtin_nontemporal_load(&sf[(size_t)row * DIM + 64 + lane]);
        float ss = x0 * x0 + x1 * x1;
        #pragma unroll
        for (int off = 32; off > 0; off >>= 1) ss += __shfl_xor(ss, off, 64);
        float rn = 1.0f / fmaxf(sqrtf(ss), 1e-8f);
        int c = lab[row];
        atomicAdd(&acc[c * DIM + lane],      x0 * rn);   // ds_add_f32, 2 lanes/bank = free
        atomicAdd(&acc[c * DIM + 64 + lane], x1 * rn);
        if (lane == 0) atomicAdd(&cnt[c], 1.0f);
    }
    __syncthreads();

    float* slot = part + (size_t)blockIdx.x * (NCLS * DIM + NCLS);
    for (int i = threadIdx.x; i < NCLS * DIM; i += 1024) slot[i] = acc[i];
    if (threadIdx.x < NCLS) slot[NCLS * DIM + threadIdx.x] = cnt[threadIdx.x];
}

// ---------------------------------------------------------------------------
// Kernel B2: reduce partials -> psq[C], pcnt[C], and MFMA-fragment-ordered
// fp16 hi/lo proto arrays pbh/pbl.
// B-frag layout for mfma_f32_16x16x32_f16: lane L holds
//   B[col = ct*16 + (L&15)][k = kk*32 + (L>>4)*8 + e], e=0..7.
// Flat half index: ((ct*4 + kk)*64 + L)*8 + e, ct=c>>4, kk=d>>5,
//   L=((d>>3)&3)*16 + (c&15), e=d&7.   (verified: col==c, k==d identically;
//   note any consistent lane->k permutation in A/B cancels in the dot product)
// grid = 256 blocks (one class each), block = 128 threads (one dim each)
// ---------------------------------------------------------------------------
__global__ __launch_bounds__(128) void proto_reduce_kernel(
    const float* __restrict__ part, int nb,
    float* __restrict__ psq, float* __restrict__ pcnt,
    _Float16* __restrict__ pbh, _Float16* __restrict__ pbl)
{
    const int c = blockIdx.x;
    const int d = threadIdx.x;
    const size_t slot = (size_t)(NCLS * DIM + NCLS);

    float s = 0.0f;
    for (int b = 0; b < nb; ++b) s += part[(size_t)b * slot + c * DIM + d];
    float cn = 0.0f;
    for (int b = 0; b < nb; ++b) cn += part[(size_t)b * slot + NCLS * DIM + c];

    float p = s / fmaxf(cn, 1.0f);

    _Float16 ph = (_Float16)p;
    _Float16 pl = (_Float16)(p - (float)ph);
    int fi = (((c >> 4) * 4 + (d >> 5)) * 64 + ((d >> 3) & 3) * 16 + (c & 15)) * 8 + (d & 7);
    pbh[fi] = ph;
    pbl[fi] = pl;

    float pp = p * p;
    #pragma unroll
    for (int off = 32; off > 0; off >>= 1) pp += __shfl_xor(pp, off, 64);
    __shared__ float tmp[2];
    if ((threadIdx.x & 63) == 0) tmp[threadIdx.x >> 6] = pp;
    __syncthreads();
    if (threadIdx.x == 0) { psq[c] = tmp[0] + tmp[1]; pcnt[c] = cn; }
}

// ---------------------------------------------------------------------------
// Kernel C: fused normalize(q) + split-fp16 MFMA GEMM + epilogue.
//   512 threads = 8 waves (2 row-groups x 4 col-groups), block tile 64x256
//   (q still read exactly once: every row tile covers all 256 classes).
//   Wave tile 32x64 = 2x4 MFMA tiles of 16x16, K=128 in 4 ksteps of 32.
//   q tile staged in LDS as fp16 hi/lo, XOR-swizzled (byte ^= (row&7)<<4):
//   k-loop ds_read_b128 banks = (kk*16 ^ (row&7)*4) mod 32 -> 2 lanes/bank
//   = free (m136). B-frags read from global pbh/pbl (L2-resident,
//   pre-swizzled to lane order). One barrier total.
//   A-frag layout: lane L holds A[row=(L&15)][k=(L>>4)*8+e].
//   D layout (HW-verified m89/m91): col=lane&15, row=(lane>>4)*4+reg.
//   VGPR est ~95 (acc 32 + afrag 32 + bfrag 16 + addr/temps) -> under the
//   (512,4) cap of 128 -> no spill risk; 2-3 blocks/CU (LDS 34.3KB).
//   q loads / out stores nontemporal: don't L2-allocate the 396 MB stream.
// ---------------------------------------------------------------------------
#define BM 64

__global__ __launch_bounds__(512, 4) void logits_mfma_kernel(
    const float* __restrict__ q,
    const float* __restrict__ psq, const float* __restrict__ pcnt,
    const _Float16* __restrict__ pbh, const _Float16* __restrict__ pbl,
    float* __restrict__ out)
{
    __shared__ char  qh_l[BM * 256];    // [row][k] fp16 hi, swizzled, 16 KB
    __shared__ char  ql_l[BM * 256];    // fp16 lo, 16 KB
    __shared__ float qsq_l[BM];
    __shared__ float psq_l[NCLS];
    __shared__ float pcnt_l[NCLS];

    const int tid  = threadIdx.x;
    const int lane = tid & 63;
    const int wid  = tid >> 6;          // 0..7
    const int wr   = wid >> 2;          // 0..1 row group (32 rows each)
    const int wc   = wid & 3;           // 0..3 col group (64 cols each)
    const int row0 = blockIdx.x * BM;

    // ---- stage q tile: read fp32 (nt), split hi/lo fp16, row sumsq ----
    #pragma unroll
    for (int it = 0; it < BM / 16; ++it) {
        const int row = it * 16 + (tid >> 5);       // 0..63, one row per 32-thread group
        const int cf  = (tid & 31) * 4;             // float idx 0..124
        f32x4 v = __builtin_nontemporal_load(
            reinterpret_cast<const f32x4*>(&q[(size_t)(row0 + row) * DIM + cf]));

        float ss = v[0] * v[0] + v[1] * v[1] + v[2] * v[2] + v[3] * v[3];
        #pragma unroll
        for (int m = 16; m > 0; m >>= 1) ss += __shfl_xor(ss, m, 64);  // 32-lane-group reduce
        if ((tid & 31) == 0) qsq_l[row] = ss;

        _Float16 h0 = (_Float16)v[0], h1 = (_Float16)v[1],
                 h2 = (_Float16)v[2], h3 = (_Float16)v[3];
        f16x4 h4 = {h0, h1, h2, h3};
        f16x4 l4 = {(_Float16)(v[0] - (float)h0), (_Float16)(v[1] - (float)h1),
                    (_Float16)(v[2] - (float)h2), (_Float16)(v[3] - (float)h3)};
        uint32_t b = (uint32_t)(row * 256 + cf * 2) ^ (uint32_t)((row & 7) << 4);
        *reinterpret_cast<f16x4*>(qh_l + b) = h4;
        *reinterpret_cast<f16x4*>(ql_l + b) = l4;
    }
    if (tid < NCLS) { psq_l[tid] = psq[tid]; pcnt_l[tid] = pcnt[tid]; }
    __syncthreads();

    // ---- MFMA k-loop ----
    f32x4 zero = {0.f, 0.f, 0.f, 0.f};
    f32x4 acc[2][4];
    #pragma unroll
    for (int i = 0; i < 2; ++i)
        #pragma unroll
        for (int j = 0; j < 4; ++j) acc[i][j] = zero;

    for (int kk = 0; kk < 4; ++kk) {
        f16x8 ah[2], al[2];
        const int k0 = kk * 32 + (lane >> 4) * 8;
        #pragma unroll
        for (int i = 0; i < 2; ++i) {
            const int row = wr * 32 + i * 16 + (lane & 15);
            uint32_t b = (uint32_t)(row * 256 + k0 * 2) ^ (uint32_t)((row & 7) << 4);
            ah[i] = *reinterpret_cast<const f16x8*>(qh_l + b);
            al[i] = *reinterpret_cast<const f16x8*>(ql_l + b);
        }
        #pragma unroll
        for (int j = 0; j < 4; ++j) {
            const int ct = wc * 4 + j;
            f16x8 bh = *reinterpret_cast<const f16x8*>(pbh + ((ct * 4 + kk) * 64 + lane) * 8);
            f16x8 bl = *reinterpret_cast<const f16x8*>(pbl + ((ct * 4 + kk) * 64 + lane) * 8);
            #pragma unroll
            for (int i = 0; i < 2; ++i) {
                acc[i][j] = __builtin_amdgcn_mfma_f32_16x16x32_f16(ah[i], bh, acc[i][j], 0, 0, 0);
                acc[i][j] = __builtin_amdgcn_mfma_f32_16x16x32_f16(al[i], bh, acc[i][j], 0, 0, 0);
                acc[i][j] = __builtin_amdgcn_mfma_f32_16x16x32_f16(ah[i], bl, acc[i][j], 0, 0, 0);
            }
        }
    }

    // ---- epilogue: fold normalization, temperature, present mask ----
    float rnv[2][4], qn2v[2][4];
    #pragma unroll
    for (int i = 0; i < 2; ++i)
        #pragma unroll
        for (int r = 0; r < 4; ++r) {
            const int rowl = wr * 32 + i * 16 + (lane >> 4) * 4 + r;
            float ss = qsq_l[rowl];
            float rn = 1.0f / fmaxf(sqrtf(ss), 1e-8f);
            rnv[i][r]  = rn;
            qn2v[i][r] = ss * rn * rn;   // == ||q_normalized||^2 (matches reference)
        }
    #pragma unroll
    for (int j = 0; j < 4; ++j) {
        const int col = wc * 64 + j * 16 + (lane & 15);
        const float pq = psq_l[col];
        const bool  pr = pcnt_l[col] > 0.5f;
        #pragma unroll
        for (int i = 0; i < 2; ++i) {
            #pragma unroll
            for (int r = 0; r < 4; ++r) {
                const int rowl = wr * 32 + i * 16 + (lane >> 4) * 4 + r;
                float v = 2.0f * (2.0f * acc[i][j][r] * rnv[i][r] - qn2v[i][r] - pq);
                __builtin_nontemporal_store(pr ? v : -1e6f,
                    &out[(size_t)(row0 + rowl) * NCLS + col]);
            }
        }
    }
}

// ---------------------------------------------------------------------------
extern "C" void kernel_launch(void* const* d_in, const int* in_sizes, int n_in,
                              void* d_out, int out_size, void* d_ws, size_t ws_size,
                              hipStream_t stream)
{
    const float* sf  = (const float*)d_in[0];
    const int*   lab = (const int*)d_in[1];
    const float* qf  = (const float*)d_in[2];
    float*       out = (float*)d_out;

    const int K = in_sizes[0] / DIM;   // 131072
    const int M = in_sizes[2] / DIM;   // 262144

    // ws layout (bytes):
    //   0      : psq   [256] f32      (1 KB)
    //   1024   : pcnt  [256] f32      (1 KB)
    //   2048   : pbh   [32768] f16    (64 KB)
    //   67584  : pbl   [32768] f16    (64 KB)
    //   133120 : part  [nb1 * 33024] f32   (nb1 <= 256 -> <= 33.9 MB)
    char* ws = (char*)d_ws;
    float*    psq  = (float*)(ws);
    float*    pcnt = (float*)(ws + 1024);
    _Float16* pbh  = (_Float16*)(ws + 2048);
    _Float16* pbl  = (_Float16*)(ws + 67584);
    float*    part = (float*)(ws + 133120);

    const size_t base_bytes = 133120;
    const size_t slot_bytes = (size_t)(NCLS * DIM + NCLS) * sizeof(float);
    int nb1 = 1;
    if (ws_size > base_bytes + slot_bytes) {
        size_t n = (ws_size - base_bytes) / slot_bytes;
        nb1 = (int)(n < 256 ? n : 256);   // 256 blocks -> all CUs busy in B1
        if (nb1 < 1) nb1 = 1;
    }

    proto_partial_kernel<<<nb1, 1024, 0, stream>>>(sf, lab, part, K, nb1);
    proto_reduce_kernel<<<NCLS, 128, 0, stream>>>(part, nb1, psq, pcnt, pbh, pbl);
    logits_mfma_kernel<<<M / BM, 512, 0, stream>>>(qf, psq, pcnt, pbh, pbl, out);
}

// Round 11
// 540.781 us; speedup vs baseline: 1.1833x; 1.1833x over previous
//
#include <hip/hip_runtime.h>
#include <hip/hip_bf16.h>

// ProtoICLHead: prototype-classifier head.
//   s = l2norm(support)  [K,128]
//   protos[c] = mean_{label==c} s          (C=256)
//   q = l2norm(query)    [M,128]
//   logits = 2 * (2*q_n@protos^T - ||q_n||^2 - ||p||^2), absent class -> -1e6
// Shapes: K=131072, M=262144, D=128, C=256. GEMM done as fp32-via-fp16-split
// (hi/lo) on MFMA: q.p = ph.qh + ph.ql + pl.qh  (lo.lo dropped).
// R9 HW result: PASSED, absmax 0.0156, dur_us 640 (incl. ~420us harness
// re-poison fills; our kernels < 162us each). R10: operand swap (A=protos,
// B=q) -> float4 epilogue stores; valid because AMD f16 MFMA A/B fragments
// share the same k-ordering (role-symmetric layouts).

#define NCLS 256
#define DIM  128

typedef _Float16 f16x8 __attribute__((ext_vector_type(8)));
typedef _Float16 f16x4 __attribute__((ext_vector_type(4)));
typedef float    f32x4 __attribute__((ext_vector_type(4)));

// ---------------------------------------------------------------------------
// Kernel B1: per-block partial prototype sums (deterministic, no global atomics)
// LDS accumulate [256][128] fp32 (128KB) + counts, then copy to ws slot.
// (unchanged from R9 passing version)
// ---------------------------------------------------------------------------
__global__ __launch_bounds__(1024) void proto_partial_kernel(
    const float* __restrict__ sf, const int* __restrict__ lab,
    float* __restrict__ part, int K, int nblocks)
{
    __shared__ float acc[NCLS * DIM];   // 128 KB
    __shared__ float cnt[NCLS];

    for (int i = threadIdx.x; i < NCLS * DIM; i += 1024) acc[i] = 0.0f;
    if (threadIdx.x < NCLS) cnt[threadIdx.x] = 0.0f;
    __syncthreads();

    const int lane = threadIdx.x & 63;
    const int wid  = (blockIdx.x * 1024 + threadIdx.x) >> 6;   // global wave id
    const int nw   = (nblocks * 1024) >> 6;

    for (int row = wid; row < K; row += nw) {
        float x0 = __builtin_nontemporal_load(&sf[(size_t)row * DIM + lane]);
        float x1 = __builtin_nontemporal_load(&sf[(size_t)row * DIM + 64 + lane]);
        float ss = x0 * x0 + x1 * x1;
        #pragma unroll
        for (int off = 32; off > 0; off >>= 1) ss += __shfl_xor(ss, off, 64);
        float rn = 1.0f / fmaxf(sqrtf(ss), 1e-8f);
        int c = lab[row];
        atomicAdd(&acc[c * DIM + lane],      x0 * rn);   // ds_add_f32, 2 lanes/bank = free
        atomicAdd(&acc[c * DIM + 64 + lane], x1 * rn);
        if (lane == 0) atomicAdd(&cnt[c], 1.0f);
    }
    __syncthreads();

    float* slot = part + (size_t)blockIdx.x * (NCLS * DIM + NCLS);
    for (int i = threadIdx.x; i < NCLS * DIM; i += 1024) slot[i] = acc[i];
    if (threadIdx.x < NCLS) slot[NCLS * DIM + threadIdx.x] = cnt[threadIdx.x];
}

// ---------------------------------------------------------------------------
// Kernel B2: reduce partials -> psq[C], pcnt[C], and MFMA-fragment-ordered
// fp16 hi/lo proto arrays pbh/pbl (layout unchanged; used as A-operand now:
// lane L holds P[row_class = ct*16 + (L&15)][k = kk*32 + (L>>4)*8 + e]).
// R10: 4-way unrolled partial-sum accumulators (MLP) + thread-parallel
// count reduction (was a 256-iteration serial broadcast loop).
// ---------------------------------------------------------------------------
__global__ __launch_bounds__(128) void proto_reduce_kernel(
    const float* __restrict__ part, int nb,
    float* __restrict__ psq, float* __restrict__ pcnt,
    _Float16* __restrict__ pbh, _Float16* __restrict__ pbl)
{
    const int c = blockIdx.x;
    const int d = threadIdx.x;
    const size_t slot = (size_t)(NCLS * DIM + NCLS);

    // proto partial sums: 4 independent accumulators for memory-level parallelism
    float s0 = 0.0f, s1 = 0.0f, s2 = 0.0f, s3 = 0.0f;
    int b = 0;
    for (; b + 3 < nb; b += 4) {
        s0 += part[(size_t)(b + 0) * slot + c * DIM + d];
        s1 += part[(size_t)(b + 1) * slot + c * DIM + d];
        s2 += part[(size_t)(b + 2) * slot + c * DIM + d];
        s3 += part[(size_t)(b + 3) * slot + c * DIM + d];
    }
    for (; b < nb; ++b) s0 += part[(size_t)b * slot + c * DIM + d];
    float s = (s0 + s1) + (s2 + s3);

    // counts: thread-parallel over partial blocks, then block reduce
    float cnp = 0.0f;
    for (int bb = d; bb < nb; bb += 128) cnp += part[(size_t)bb * slot + NCLS * DIM + c];
    #pragma unroll
    for (int off = 32; off > 0; off >>= 1) cnp += __shfl_xor(cnp, off, 64);
    __shared__ float cn_l[2];
    if ((d & 63) == 0) cn_l[d >> 6] = cnp;
    __syncthreads();
    const float cn = cn_l[0] + cn_l[1];

    float p = s / fmaxf(cn, 1.0f);

    _Float16 ph = (_Float16)p;
    _Float16 pl = (_Float16)(p - (float)ph);
    int fi = (((c >> 4) * 4 + (d >> 5)) * 64 + ((d >> 3) & 3) * 16 + (c & 15)) * 8 + (d & 7);
    pbh[fi] = ph;
    pbl[fi] = pl;

    float pp = p * p;
    #pragma unroll
    for (int off = 32; off > 0; off >>= 1) pp += __shfl_xor(pp, off, 64);
    __shared__ float tmp[2];
    if ((d & 63) == 0) tmp[d >> 6] = pp;
    __syncthreads();
    if (d == 0) { psq[c] = tmp[0] + tmp[1]; pcnt[c] = cn; }
}

// ---------------------------------------------------------------------------
// Kernel C: fused normalize(q) + split-fp16 MFMA GEMM + epilogue.
//   512 threads = 8 waves (2 row-groups x 4 col-groups), block tile 64x256.
//   OPERAND SWAP — A = proto fragment, B = q fragment, so D[class][qrow]:
//   lane L holds qrow = tile + (L&15), classes = (L>>4)*4 + reg (4
//   CONSECUTIVE classes) -> float4 epilogue stores (8 per thread, each
//   instr = 16 rows x 64B contiguous segments). Both fragment mappings
//   HW-validated by the R9 passing run; A/B layouts are role-symmetric with
//   identical k-ordering, so the swap preserves correctness. LDS q reads
//   and global pbh/pbl reads are byte-identical to R9.
//   q tile staged in LDS as fp16 hi/lo, XOR-swizzled (byte ^= (row&7)<<4).
//   VGPR est ~95 -> under the (512,4) cap of 128; LDS 34.5KB -> 2 blocks/CU.
// ---------------------------------------------------------------------------
#define BM 64

__global__ __launch_bounds__(512, 4) void logits_mfma_kernel(
    const float* __restrict__ q,
    const float* __restrict__ psq, const float* __restrict__ pcnt,
    const _Float16* __restrict__ pbh, const _Float16* __restrict__ pbl,
    float* __restrict__ out)
{
    __shared__ char  qh_l[BM * 256];    // [row][k] fp16 hi, swizzled, 16 KB
    __shared__ char  ql_l[BM * 256];    // fp16 lo, 16 KB
    __shared__ float qsq_l[BM];
    __shared__ float psq_l[NCLS];
    __shared__ float pcnt_l[NCLS];

    const int tid  = threadIdx.x;
    const int lane = tid & 63;
    const int wid  = tid >> 6;          // 0..7
    const int wr   = wid >> 2;          // 0..1 row group (32 rows each)
    const int wc   = wid & 3;           // 0..3 col group (64 classes each)
    const int row0 = blockIdx.x * BM;

    // ---- stage q tile: read fp32 (nt), split hi/lo fp16, row sumsq ----
    #pragma unroll
    for (int it = 0; it < BM / 16; ++it) {
        const int row = it * 16 + (tid >> 5);       // 0..63, one row per 32-thread group
        const int cf  = (tid & 31) * 4;             // float idx 0..124
        f32x4 v = __builtin_nontemporal_load(
            reinterpret_cast<const f32x4*>(&q[(size_t)(row0 + row) * DIM + cf]));

        float ss = v[0] * v[0] + v[1] * v[1] + v[2] * v[2] + v[3] * v[3];
        #pragma unroll
        for (int m = 16; m > 0; m >>= 1) ss += __shfl_xor(ss, m, 64);  // 32-lane-group reduce
        if ((tid & 31) == 0) qsq_l[row] = ss;

        _Float16 h0 = (_Float16)v[0], h1 = (_Float16)v[1],
                 h2 = (_Float16)v[2], h3 = (_Float16)v[3];
        f16x4 h4 = {h0, h1, h2, h3};
        f16x4 l4 = {(_Float16)(v[0] - (float)h0), (_Float16)(v[1] - (float)h1),
                    (_Float16)(v[2] - (float)h2), (_Float16)(v[3] - (float)h3)};
        uint32_t bofs = (uint32_t)(row * 256 + cf * 2) ^ (uint32_t)((row & 7) << 4);
        *reinterpret_cast<f16x4*>(qh_l + bofs) = h4;
        *reinterpret_cast<f16x4*>(ql_l + bofs) = l4;
    }
    if (tid < NCLS) { psq_l[tid] = psq[tid]; pcnt_l[tid] = pcnt[tid]; }
    __syncthreads();

    // ---- MFMA k-loop: acc[j][i] = P_tile(j) . Q_tile(i)^T ----
    f32x4 zero = {0.f, 0.f, 0.f, 0.f};
    f32x4 acc[4][2];
    #pragma unroll
    for (int j = 0; j < 4; ++j)
        #pragma unroll
        for (int i = 0; i < 2; ++i) acc[j][i] = zero;

    for (int kk = 0; kk < 4; ++kk) {
        f16x8 qbh[2], qbl[2];
        const int k0 = kk * 32 + (lane >> 4) * 8;
        #pragma unroll
        for (int i = 0; i < 2; ++i) {
            const int row = wr * 32 + i * 16 + (lane & 15);
            uint32_t bofs = (uint32_t)(row * 256 + k0 * 2) ^ (uint32_t)((row & 7) << 4);
            qbh[i] = *reinterpret_cast<const f16x8*>(qh_l + bofs);
            qbl[i] = *reinterpret_cast<const f16x8*>(ql_l + bofs);
        }
        #pragma unroll
        for (int j = 0; j < 4; ++j) {
            const int ct = wc * 4 + j;
            f16x8 pah = *reinterpret_cast<const f16x8*>(pbh + ((ct * 4 + kk) * 64 + lane) * 8);
            f16x8 pal = *reinterpret_cast<const f16x8*>(pbl + ((ct * 4 + kk) * 64 + lane) * 8);
            #pragma unroll
            for (int i = 0; i < 2; ++i) {
                acc[j][i] = __builtin_amdgcn_mfma_f32_16x16x32_f16(pah, qbh[i], acc[j][i], 0, 0, 0);
                acc[j][i] = __builtin_amdgcn_mfma_f32_16x16x32_f16(pah, qbl[i], acc[j][i], 0, 0, 0);
                acc[j][i] = __builtin_amdgcn_mfma_f32_16x16x32_f16(pal, qbh[i], acc[j][i], 0, 0, 0);
            }
        }
    }

    // ---- epilogue: per lane, qrow = f(lane&15, i); 4 consecutive classes/reg ----
    #pragma unroll
    for (int i = 0; i < 2; ++i) {
        const int qrow = wr * 32 + i * 16 + (lane & 15);
        const float ss = qsq_l[qrow];
        const float rn = 1.0f / fmaxf(sqrtf(ss), 1e-8f);
        const float qn2 = ss * rn * rn;   // == ||q_normalized||^2 (matches reference)
        #pragma unroll
        for (int j = 0; j < 4; ++j) {
            const int cb = wc * 64 + j * 16 + (lane >> 4) * 4;   // class base (16B-aligned)
            float tmp4[4];
            #pragma unroll
            for (int r = 0; r < 4; ++r) {
                float v = 2.0f * (2.0f * acc[j][i][r] * rn - qn2 - psq_l[cb + r]);
                tmp4[r] = (pcnt_l[cb + r] > 0.5f) ? v : -1e6f;
            }
            __builtin_nontemporal_store(*reinterpret_cast<const f32x4*>(tmp4),
                reinterpret_cast<f32x4*>(&out[(size_t)(row0 + qrow) * NCLS + cb]));
        }
    }
}

// ---------------------------------------------------------------------------
extern "C" void kernel_launch(void* const* d_in, const int* in_sizes, int n_in,
                              void* d_out, int out_size, void* d_ws, size_t ws_size,
                              hipStream_t stream)
{
    const float* sf  = (const float*)d_in[0];
    const int*   lab = (const int*)d_in[1];
    const float* qf  = (const float*)d_in[2];
    float*       out = (float*)d_out;

    const int K = in_sizes[0] / DIM;   // 131072
    const int M = in_sizes[2] / DIM;   // 262144

    // ws layout (bytes):
    //   0      : psq   [256] f32      (1 KB)
    //   1024   : pcnt  [256] f32      (1 KB)
    //   2048   : pbh   [32768] f16    (64 KB)
    //   67584  : pbl   [32768] f16    (64 KB)
    //   133120 : part  [nb1 * 33024] f32   (nb1 <= 256 -> <= 33.9 MB)
    char* ws = (char*)d_ws;
    float*    psq  = (float*)(ws);
    float*    pcnt = (float*)(ws + 1024);
    _Float16* pbh  = (_Float16*)(ws + 2048);
    _Float16* pbl  = (_Float16*)(ws + 67584);
    float*    part = (float*)(ws + 133120);

    const size_t base_bytes = 133120;
    const size_t slot_bytes = (size_t)(NCLS * DIM + NCLS) * sizeof(float);
    int nb1 = 1;
    if (ws_size > base_bytes + slot_bytes) {
        size_t n = (ws_size - base_bytes) / slot_bytes;
        nb1 = (int)(n < 256 ? n : 256);   // 256 blocks -> all CUs busy in B1
        if (nb1 < 1) nb1 = 1;
    }

    proto_partial_kernel<<<nb1, 1024, 0, stream>>>(sf, lab, part, K, nb1);
    proto_reduce_kernel<<<NCLS, 128, 0, stream>>>(part, nb1, psq, pcnt, pbh, pbl);
    logits_mfma_kernel<<<M / BM, 512, 0, stream>>>(qf, psq, pcnt, pbh, pbl, out);
}